// Round 5
// baseline (838.031 us; speedup 1.0000x reference)
//
#include <hip/hip_runtime.h>
#include <math.h>

// LRENet_2: L=4, AD=D=512, T=64, N=4096, NC=2, PROJ=256, HID=2048, CAP=16
#define LNUM 4
#define ADIM 512
#define TTOK 64
#define NSEQ 4096
#define HIDE 2048
#define CAPE 16
#define EPSV 1e-5f
#define LOG2E 1.44269504088896340736f

typedef __bf16 bf16;
typedef bf16 bf16x8 __attribute__((ext_vector_type(8)));
typedef float f32x4 __attribute__((ext_vector_type(4)));

// ---------------- workspace layout (float offsets) ----------------
// zero region (atomic-GEMM outputs + MoE buf) first, zeroed every launch
#define OFF_BUF   0
#define OFF_SSUM  (OFF_BUF  + 131072)
#define OFF_CNT   (OFF_SSUM + 16)
#define OFF_Q     (OFF_CNT  + 16)
#define OFF_AP    (OFF_Q    + 131072)
#define OFF_QF    (OFF_AP   + 131072)
#define OFF_P     (OFF_QF   + 131072)
#define OFF_QKV3  (OFF_P    + 65536)
#define OFF_XB    (OFF_QKV3 + 98304)
#define OFF_HROW  (OFF_XB   + 32768)
#define OFF_GTD   (OFF_HROW + 131072)
#define OFF_HB    (OFF_GTD  + 32768)
#define ZERO_N    (OFF_HB   + 16384)
// non-zeroed
#define OFF_KT    ZERO_N
#define OFF_VT    (OFF_KT   + LNUM*512*NSEQ)
#define OFF_AO    (OFF_VT   + LNUM*512*NSEQ)  // shared: TN -> AO -> XN2 -> XN3 (sequential lifetimes)
#define OFF_GATE  (OFF_AO   + 131072)
#define OFF_EXP   (OFF_GATE + 256)
#define OFF_POS   (OFF_EXP  + 256)
#define OFF_KEEP  (OFF_POS  + 256)
#define OFF_HEXP  (OFF_KEEP + 256)
#define OFF_CUR   (OFF_HEXP + LNUM*4*CAPE*HIDE)
#define OFF_AO2   (OFF_CUR  + TTOK*512)
#define OFF_AH    (OFF_AO2  + TTOK*512)   // bf16 (float slots = half count); YEXP aliases (AH dead post-mfma)
#define OFF_AL    (OFF_AH + LNUM*NSEQ*256)
#define OFF_WH    (OFF_AL + LNUM*NSEQ*256)
#define OFF_WL    (OFF_WH + LNUM*1024*256)
#define OFF_YEXP  OFF_AH

// ---------------- output layout (floats) ----------------
#define O_F1   6
#define O_F2   (6 + LNUM*TTOK*512)
#define O_F2P  (O_F2 + LNUM*TTOK*512)

__device__ __forceinline__ float wave_sum(float v) {
#pragma unroll
  for (int o = 32; o > 0; o >>= 1) v += __shfl_down(v, o, 64);
  return v;
}
__device__ __forceinline__ float wave_sum_all(float v) {
#pragma unroll
  for (int o = 32; o > 0; o >>= 1) v += __shfl_xor(v, o, 64);
  return v;
}
__device__ __forceinline__ float block_sum256(float v) {
  __shared__ float r[4];
  v = wave_sum(v);
  int wid = threadIdx.x >> 6, lane = threadIdx.x & 63;
  if (lane == 0) r[wid] = v;
  __syncthreads();
  float s = r[0] + r[1] + r[2] + r[3];
  __syncthreads();
  return s;
}

// ---------------- zero scratch ----------------
__global__ void k_zero(float* __restrict__ p, int n) {
  int i = blockIdx.x * 256 + threadIdx.x;
  if (i < n) p[i] = 0.f;
}

// ---------------- LN + split-bf16 convert of A panel ----------------
__global__ __launch_bounds__(64) void k_cvt_a(const float* __restrict__ SF,
      const float* __restrict__ G, const float* __restrict__ Bta,
      bf16* __restrict__ AH, bf16* __restrict__ AL) {
  int row = blockIdx.x;            // l*4096 + m
  int l = row >> 12, m = row & 4095;
  int lane = threadIdx.x;
  const float* src = SF + (size_t)m * (LNUM * ADIM) + l * ADIM;
  float4 a = *(const float4*)(src + lane * 8);
  float4 b = *(const float4*)(src + lane * 8 + 4);
  float sum = (a.x + a.y) + (a.z + a.w) + (b.x + b.y) + (b.z + b.w);
  float sq = a.x*a.x + a.y*a.y + a.z*a.z + a.w*a.w + b.x*b.x + b.y*b.y + b.z*b.z + b.w*b.w;
  sum = wave_sum_all(sum); sq = wave_sum_all(sq);
  float mu = sum * (1.f / 512.f);
  float rs = rsqrtf(sq * (1.f / 512.f) - mu * mu + EPSV);
  float4 g0 = *(const float4*)(G + l * 512 + lane * 8);
  float4 g1 = *(const float4*)(G + l * 512 + lane * 8 + 4);
  float4 c0 = *(const float4*)(Bta + l * 512 + lane * 8);
  float4 c1 = *(const float4*)(Bta + l * 512 + lane * 8 + 4);
  float x[8];
  x[0] = (a.x - mu) * rs * g0.x + c0.x;  x[1] = (a.y - mu) * rs * g0.y + c0.y;
  x[2] = (a.z - mu) * rs * g0.z + c0.z;  x[3] = (a.w - mu) * rs * g0.w + c0.w;
  x[4] = (b.x - mu) * rs * g1.x + c1.x;  x[5] = (b.y - mu) * rs * g1.y + c1.y;
  x[6] = (b.z - mu) * rs * g1.z + c1.z;  x[7] = (b.w - mu) * rs * g1.w + c1.w;
  bf16x8 vh, vl;
#pragma unroll
  for (int j = 0; j < 8; j++) {
    bf16 h = (bf16)x[j];
    vh[j] = h;
    vl[j] = (bf16)(x[j] - (float)h);
  }
  *(bf16x8*)(AH + (size_t)row * 512 + lane * 8) = vh;
  *(bf16x8*)(AL + (size_t)row * 512 + lane * 8) = vl;
}

// ---------------- split-bf16 convert of W K/V rows ----------------
__global__ __launch_bounds__(64) void k_cvt_w(const float* __restrict__ Wqkv,
      bf16* __restrict__ WH, bf16* __restrict__ WL) {
  int row = blockIdx.x;            // l*1024 + r
  int l = row >> 10, r = row & 1023;
  int lane = threadIdx.x;
  const float* src = Wqkv + (size_t)l * 1536 * 512 + (size_t)(512 + r) * 512 + lane * 8;
  float4 a = *(const float4*)(src);
  float4 b = *(const float4*)(src + 4);
  float x[8] = {a.x, a.y, a.z, a.w, b.x, b.y, b.z, b.w};
  bf16x8 vh, vl;
#pragma unroll
  for (int j = 0; j < 8; j++) {
    bf16 h = (bf16)x[j];
    vh[j] = h;
    vl[j] = (bf16)(x[j] - (float)h);
  }
  *(bf16x8*)(WH + (size_t)row * 512 + lane * 8) = vh;
  *(bf16x8*)(WL + (size_t)row * 512 + lane * 8) = vl;
}

// ---------------- split-bf16 MFMA GEMM -> K^T, V^T ----------------
// grid (x = m-tile [32], y = n-tile [8], z = L): the 8 n-blocks sharing an
// A-panel are 32 apart in linear id -> same XCD (32 % 8 == 0) -> A hits L2.
__global__ __launch_bounds__(256) void k_mfma_kv(
      const bf16* __restrict__ AH, const bf16* __restrict__ AL,
      const bf16* __restrict__ WH, const bf16* __restrict__ WL,
      const float* __restrict__ Bqkv,
      float* __restrict__ KT, float* __restrict__ VT) {
  __shared__ bf16 sAh[128*32], sAl[128*32], sWh[128*32], sWl[128*32];
  int l = blockIdx.z;
  int m0 = blockIdx.x * 128, n0 = blockIdx.y * 128;
  int tid = threadIdx.x;
  int lane = tid & 63;
  int w = tid >> 6;
  int wm = w >> 1, wn = w & 1;
  const bf16* gAh = AH + ((size_t)l * 4096 + m0) * 512;
  const bf16* gAl = AL + ((size_t)l * 4096 + m0) * 512;
  const bf16* gWh = WH + ((size_t)l * 1024 + n0) * 512;
  const bf16* gWl = WL + ((size_t)l * 1024 + n0) * 512;
  int ch0 = tid * 2, ch1 = tid * 2 + 1;
  int r0 = ch0 >> 2, q0 = (ch0 & 3) * 8;
  int r1 = ch1 >> 2, q1 = (ch1 & 3) * 8;
  int fr = lane & 15, fq = (lane >> 4) * 8;
  f32x4 acc[4][4] = {};
  for (int k0 = 0; k0 < 512; k0 += 32) {
    *(bf16x8*)&sAh[r0*32 + q0] = *(const bf16x8*)&gAh[(size_t)r0*512 + k0 + q0];
    *(bf16x8*)&sAh[r1*32 + q1] = *(const bf16x8*)&gAh[(size_t)r1*512 + k0 + q1];
    *(bf16x8*)&sAl[r0*32 + q0] = *(const bf16x8*)&gAl[(size_t)r0*512 + k0 + q0];
    *(bf16x8*)&sAl[r1*32 + q1] = *(const bf16x8*)&gAl[(size_t)r1*512 + k0 + q1];
    *(bf16x8*)&sWh[r0*32 + q0] = *(const bf16x8*)&gWh[(size_t)r0*512 + k0 + q0];
    *(bf16x8*)&sWh[r1*32 + q1] = *(const bf16x8*)&gWh[(size_t)r1*512 + k0 + q1];
    *(bf16x8*)&sWl[r0*32 + q0] = *(const bf16x8*)&gWl[(size_t)r0*512 + k0 + q0];
    *(bf16x8*)&sWl[r1*32 + q1] = *(const bf16x8*)&gWl[(size_t)r1*512 + k0 + q1];
    __syncthreads();
    bf16x8 ah[4], al[4], bh[4], bl[4];
#pragma unroll
    for (int i = 0; i < 4; i++) {
      ah[i] = *(const bf16x8*)&sAh[(wm*64 + i*16 + fr)*32 + fq];
      al[i] = *(const bf16x8*)&sAl[(wm*64 + i*16 + fr)*32 + fq];
      bh[i] = *(const bf16x8*)&sWh[(wn*64 + i*16 + fr)*32 + fq];
      bl[i] = *(const bf16x8*)&sWl[(wn*64 + i*16 + fr)*32 + fq];
    }
#pragma unroll
    for (int i = 0; i < 4; i++)
#pragma unroll
      for (int j = 0; j < 4; j++) {
        acc[i][j] = __builtin_amdgcn_mfma_f32_16x16x32_bf16(ah[i], bh[j], acc[i][j], 0, 0, 0);
        acc[i][j] = __builtin_amdgcn_mfma_f32_16x16x32_bf16(ah[i], bl[j], acc[i][j], 0, 0, 0);
        acc[i][j] = __builtin_amdgcn_mfma_f32_16x16x32_bf16(al[i], bh[j], acc[i][j], 0, 0, 0);
      }
    __syncthreads();
  }
#pragma unroll
  for (int j = 0; j < 4; j++) {
    int n = n0 + wn*64 + j*16 + fr;
    float bias = Bqkv[l * 1536 + 512 + n];
    float* base = (n < 512) ? (KT + ((size_t)(l*512 + n)) * 4096)
                            : (VT + ((size_t)(l*512 + n - 512)) * 4096);
#pragma unroll
    for (int i = 0; i < 4; i++) {
      int mb = m0 + wm*64 + i*16 + (lane >> 4) * 4;
      float4 o = make_float4(acc[i][j][0] + bias, acc[i][j][1] + bias,
                             acc[i][j][2] + bias, acc[i][j][3] + bias);
      *(float4*)(base + mb) = o;
    }
  }
}

// ---------------- generic row LayerNorm (64 rows per l) ----------------
__global__ __launch_bounds__(64) void k_ln(const float* __restrict__ IN,
      const float* __restrict__ G, const float* __restrict__ B,
      float* __restrict__ OUT, int gstride) {
  int t = blockIdx.x, l = blockIdx.y;
  int row = l * 64 + t;
  int lane = threadIdx.x;
  const float* x = IN + (size_t)row * 512 + lane * 8;
  float4 a = ((const float4*)x)[0], b = ((const float4*)x)[1];
  float sum = (a.x + a.y) + (a.z + a.w) + (b.x + b.y) + (b.z + b.w);
  float sq = a.x*a.x + a.y*a.y + a.z*a.z + a.w*a.w + b.x*b.x + b.y*b.y + b.z*b.z + b.w*b.w;
  sum = wave_sum_all(sum); sq = wave_sum_all(sq);
  float mu = sum * (1.f / 512.f);
  float rs = rsqrtf(sq * (1.f / 512.f) - mu * mu + EPSV);
  const float* gp = G + l * gstride + lane * 8;
  const float* bp = B + l * gstride + lane * 8;
  float4 g0 = ((const float4*)gp)[0], g1 = ((const float4*)gp)[1];
  float4 c0 = ((const float4*)bp)[0], c1 = ((const float4*)bp)[1];
  float4 o0, o1;
  o0.x = (a.x - mu) * rs * g0.x + c0.x;  o0.y = (a.y - mu) * rs * g0.y + c0.y;
  o0.z = (a.z - mu) * rs * g0.z + c0.z;  o0.w = (a.w - mu) * rs * g0.w + c0.w;
  o1.x = (b.x - mu) * rs * g1.x + c1.x;  o1.y = (b.y - mu) * rs * g1.y + c1.y;
  o1.z = (b.z - mu) * rs * g1.z + c1.z;  o1.w = (b.w - mu) * rs * g1.w + c1.w;
  float* op = OUT + (size_t)row * 512 + lane * 8;
  ((float4*)op)[0] = o0; ((float4*)op)[1] = o1;
}

// ---------------- generic split-K GEMM: OUT[64t x N] (+)= IN[64t x K] @ W[N x K]^T ----------------
// grid (N/64, splitY, L). If gridDim.y>1: split-K with atomics (OUT pre-zeroed, kc chunk 128).
// If gridDim.y==1: whole-K, direct store, optional activation (act==1 -> swish).
__global__ __launch_bounds__(256) void k_gemm64(
      const float* __restrict__ IN, const float* __restrict__ W,
      const float* __restrict__ BIAS, const float* __restrict__ RES,
      float* __restrict__ OUT, int K, int N, long wl, int bl, int act) {
  int l = blockIdx.z;
  int n0 = blockIdx.x * 64;
  bool split = (gridDim.y > 1);
  int kcBeg = blockIdx.y * 128;
  int kcEnd = split ? kcBeg + 128 : K;
  const float* INl = IN + (size_t)l * 64 * K;
  const float* Wl  = W + (size_t)l * wl;
  float* OUTl = OUT + (size_t)l * 64 * N;
  __shared__ float sA[64][68], sB[64][68];
  int tid = threadIdx.x;
  int tx = tid & 15, ty = tid >> 4;
  float acc[4][4];
  if (blockIdx.y == 0) {
#pragma unroll
    for (int j = 0; j < 4; j++) {
      float bv = BIAS ? BIAS[bl * l + n0 + tx*4 + j] : 0.f;
#pragma unroll
      for (int i = 0; i < 4; i++)
        acc[i][j] = bv + (RES ? RES[((size_t)l*64 + ty*4 + i) * N + n0 + tx*4 + j] : 0.f);
    }
  } else {
#pragma unroll
    for (int i = 0; i < 4; i++)
#pragma unroll
      for (int j = 0; j < 4; j++) acc[i][j] = 0.f;
  }
  for (int kc = kcBeg; kc < kcEnd; kc += 64) {
    for (int i = tid; i < 1024; i += 256) {
      int r = i >> 4;
      int kq = i & 15;
      float4 av = *(const float4*)(INl + (size_t)r * K + kc + kq*4);
      sA[kq*4+0][r] = av.x; sA[kq*4+1][r] = av.y; sA[kq*4+2][r] = av.z; sA[kq*4+3][r] = av.w;
      float4 bv = *(const float4*)(Wl + (size_t)(n0 + r) * K + kc + kq*4);
      sB[kq*4+0][r] = bv.x; sB[kq*4+1][r] = bv.y; sB[kq*4+2][r] = bv.z; sB[kq*4+3][r] = bv.w;
    }
    __syncthreads();
#pragma unroll 8
    for (int kk = 0; kk < 64; kk++) {
      float4 a4 = *(const float4*)&sA[kk][ty*4];
      float4 b4 = *(const float4*)&sB[kk][tx*4];
      float a[4] = {a4.x,a4.y,a4.z,a4.w}, b[4] = {b4.x,b4.y,b4.z,b4.w};
#pragma unroll
      for (int i = 0; i < 4; i++)
#pragma unroll
        for (int j = 0; j < 4; j++) acc[i][j] = fmaf(a[i], b[j], acc[i][j]);
    }
    __syncthreads();
  }
  if (split) {
#pragma unroll
    for (int i = 0; i < 4; i++)
#pragma unroll
      for (int j = 0; j < 4; j++)
        atomicAdd(&OUTl[(size_t)(ty*4+i) * N + n0 + tx*4 + j], acc[i][j]);
  } else {
#pragma unroll
    for (int i = 0; i < 4; i++)
#pragma unroll
      for (int j = 0; j < 4; j++) {
        float o = acc[i][j];
        if (act == 1) o = o / (1.f + __expf(-1.702f * o));
        OUTl[(size_t)(ty*4+i) * N + n0 + tx*4 + j] = o;
      }
  }
}

// ---------------- transposed-W variant: W stored [K][N] (for gate proj) ----------------
__global__ __launch_bounds__(256) void k_gemm64t(
      const float* __restrict__ IN, const float* __restrict__ W,
      float* __restrict__ OUT, int K, int N) {
  int l = blockIdx.z;
  int n0 = blockIdx.x * 64;
  int kc0 = blockIdx.y * 128;
  const float* INl = IN + (size_t)l * 64 * K;
  float* OUTl = OUT + (size_t)l * 64 * N;
  __shared__ float sA[64][68], sB[64][68];
  int tid = threadIdx.x;
  int tx = tid & 15, ty = tid >> 4;
  float acc[4][4] = {};
  for (int kc = kc0; kc < kc0 + 128; kc += 64) {
    for (int i = tid; i < 1024; i += 256) {
      int r = i >> 4;
      int kq = i & 15;
      float4 av = *(const float4*)(INl + (size_t)r * K + kc + kq*4);
      sA[kq*4+0][r] = av.x; sA[kq*4+1][r] = av.y; sA[kq*4+2][r] = av.z; sA[kq*4+3][r] = av.w;
      float4 bv = *(const float4*)(W + (size_t)(kc + r) * N + n0 + kq*4);
      *(float4*)&sB[r][kq*4] = bv;
    }
    __syncthreads();
#pragma unroll 8
    for (int kk = 0; kk < 64; kk++) {
      float4 a4 = *(const float4*)&sA[kk][ty*4];
      float4 b4 = *(const float4*)&sB[kk][tx*4];
      float a[4] = {a4.x,a4.y,a4.z,a4.w}, b[4] = {b4.x,b4.y,b4.z,b4.w};
#pragma unroll
      for (int i = 0; i < 4; i++)
#pragma unroll
        for (int j = 0; j < 4; j++) acc[i][j] = fmaf(a[i], b[j], acc[i][j]);
    }
    __syncthreads();
  }
#pragma unroll
  for (int i = 0; i < 4; i++)
#pragma unroll
    for (int j = 0; j < 4; j++)
      atomicAdd(&OUTl[(size_t)(ty*4+i) * N + n0 + tx*4 + j], acc[i][j]);
}

// ---------------- hd=1 attention: register K/V, fused min/max, LDS partial reduce ----------------
// block = (h,l), 4 waves x 1024 s each; per-t exp2 loop from registers, zero loop loads.
__global__ __launch_bounds__(256) void k_attn(const float* __restrict__ KT, const float* __restrict__ VT,
      const float* __restrict__ Q, float* __restrict__ AO) {
  int h = blockIdx.x, l = blockIdx.y;
  int tid = threadIdx.x;
  int w = tid >> 6, lane = tid & 63;
  __shared__ float2 sacc[4][16][65];
  __shared__ float wmx[4], wmn[4];
  size_t base = ((size_t)(l * 512 + h)) * 4096 + w * 1024;
  float kv[16], vv[16];
#pragma unroll
  for (int c = 0; c < 4; c++) {
    *(float4*)&kv[c*4] = *(const float4*)(KT + base + c * 256 + lane * 4);
    *(float4*)&vv[c*4] = *(const float4*)(VT + base + c * 256 + lane * 4);
  }
  // fused per-head k min/max (replaces k_minmax kernel)
  float mx = kv[0], mn = kv[0];
#pragma unroll
  for (int i = 1; i < 16; i++) { mx = fmaxf(mx, kv[i]); mn = fminf(mn, kv[i]); }
#pragma unroll
  for (int o = 32; o > 0; o >>= 1) {
    mx = fmaxf(mx, __shfl_xor(mx, o, 64));
    mn = fminf(mn, __shfl_xor(mn, o, 64));
  }
  if (lane == 0) { wmx[w] = mx; wmn[w] = mn; }
  __syncthreads();
  float km = fmaxf(fmaxf(wmx[0], wmx[1]), fmaxf(wmx[2], wmx[3]));
  float kn = fminf(fminf(wmn[0], wmn[1]), fminf(wmn[2], wmn[3]));
  // per-lane q (lane = token), fold log2e
  float q_own = Q[((size_t)l * TTOK + lane) * 512 + h];
  float q2_own = q_own * LOG2E;
  float m2_own = ((q_own >= 0.f) ? q_own * km : q_own * kn) * LOG2E;  // exact max (hd=1)
  int rt = tid >> 4, rj = tid & 15;
  for (int cc = 0; cc < 4; cc++) {
    for (int tt = 0; tt < 16; tt++) {
      int t = cc * 16 + tt;
      float q2t = __shfl(q2_own, t, 64);
      float m2t = __shfl(m2_own, t, 64);
      float den = 0.f, num = 0.f;
#pragma unroll
      for (int i = 0; i < 16; i++) {
        float e = exp2f(fmaf(q2t, kv[i], -m2t));
        den += e;
        num = fmaf(e, vv[i], num);
      }
      sacc[w][tt][lane] = make_float2(den, num);
    }
    __syncthreads();
    // reduce 256 partials per t: 16 threads per t, 16 reads each, then shfl width-16
    float2 a = make_float2(0.f, 0.f);
#pragma unroll
    for (int g = 0; g < 4; g++)
#pragma unroll
      for (int s4 = 0; s4 < 4; s4++) {
        float2 v = sacc[g][rt][rj + 16 * s4];
        a.x += v.x; a.y += v.y;
      }
#pragma unroll
    for (int o = 8; o > 0; o >>= 1) {
      a.x += __shfl_down(a.x, o, 16);
      a.y += __shfl_down(a.y, o, 16);
    }
    if (rj == 0) {
      int t = cc * 16 + rt;
      AO[((size_t)l * TTOK + t) * 512 + h] = a.y / a.x;
    }
    __syncthreads();
  }
}

// ---------------- fused MoE gate + route + scatter (one block per layer) ----------------
__global__ __launch_bounds__(256) void k_moe_gate(const float* __restrict__ P,
      const float* __restrict__ SIM, const float* __restrict__ TEMP,
      const float* __restrict__ QF,
      float* __restrict__ gate, int* __restrict__ expert,
      int* __restrict__ pos, int* __restrict__ keep,
      float* __restrict__ ssum, int* __restrict__ cnt, float* __restrict__ buf) {
  int l = blockIdx.x;
  int tid = threadIdx.x;
  int t = tid >> 2, q = tid & 3;     // 4 threads per token, 64 proj dims each
  __shared__ float score_s[4][64];
  __shared__ float g_s[64];
  __shared__ int e_s[64], keep_s[64], pos_s[64];
  const float* prow = P + ((size_t)(l * 64 + t)) * 256 + q * 64;
  float ss = 0.f, le[4] = {}, ne[4] = {};
  for (int j = 0; j < 64; j++) {
    float pv = prow[j];
    ss = fmaf(pv, pv, ss);
    float4 s4 = *(const float4*)(SIM + (size_t)(q * 64 + j) * 4);
    le[0] = fmaf(pv, s4.x, le[0]); le[1] = fmaf(pv, s4.y, le[1]);
    le[2] = fmaf(pv, s4.z, le[2]); le[3] = fmaf(pv, s4.w, le[3]);
    ne[0] = fmaf(s4.x, s4.x, ne[0]); ne[1] = fmaf(s4.y, s4.y, ne[1]);
    ne[2] = fmaf(s4.z, s4.z, ne[2]); ne[3] = fmaf(s4.w, s4.w, ne[3]);
  }
#pragma unroll
  for (int o = 2; o > 0; o >>= 1) {
    ss += __shfl_xor(ss, o, 4);
#pragma unroll
    for (int e = 0; e < 4; e++) { le[e] += __shfl_xor(le[e], o, 4); ne[e] += __shfl_xor(ne[e], o, 4); }
  }
  if (q == 0) {
    float invp = 1.f / (sqrtf(ss) + 1e-8f);
    float scale = __expf(fminf(TEMP[0], 4.6051701859880914f));  // min(temp, log 100)
    float lg[4];
#pragma unroll
    for (int e = 0; e < 4; e++) lg[e] = le[e] * invp / (sqrtf(ne[e]) + 1e-8f) * scale;
    int best = 0; float bv = lg[0];
    if (lg[1] > bv) { best = 1; bv = lg[1]; }
    if (lg[2] > bv) { best = 2; bv = lg[2]; }
    if (lg[3] > bv) { best = 3; bv = lg[3]; }
    float mx = fmaxf(fmaxf(lg[0], lg[1]), fmaxf(lg[2], lg[3]));
    float e0 = __expf(lg[0]-mx), e1 = __expf(lg[1]-mx), e2 = __expf(lg[2]-mx), e3 = __expf(lg[3]-mx);
    float inv = 1.f / (e0 + e1 + e2 + e3);
    score_s[0][t] = e0*inv; score_s[1][t] = e1*inv; score_s[2][t] = e2*inv; score_s[3][t] = e3*inv;
    float sb = score_s[best][t];
    g_s[t] = sb; e_s[t] = best;
    gate[l * TTOK + t] = sb;
    expert[l * TTOK + t] = best;
  }
  __syncthreads();
  if (tid < 64) {
    float gt = g_s[tid]; int et = e_s[tid];
    int p = 0;
    for (int u = 0; u < 64; u++)
      if (e_s[u] == et && (g_s[u] > gt || (g_s[u] == gt && u < tid))) p++;
    pos_s[tid] = p; keep_s[tid] = (p < CAPE) ? 1 : 0;
    pos[l * TTOK + tid] = p;
    keep[l * TTOK + tid] = (p < CAPE) ? 1 : 0;
  } else if (tid < 68) {
    int e = tid - 64;
    float s = 0.f; int c = 0;
    for (int u = 0; u < 64; u++) { s += score_s[e][u]; c += (e_s[u] == e); }
    ssum[l * 4 + e] = s;
    cnt[l * 4 + e] = c;
  }
  __syncthreads();
  int which = tid >> 7, idx = tid & 127;   // 2 tokens per iteration, 128 float4 each
  for (int tb = 0; tb < 64; tb += 2) {
    int tt = tb + which;
    if (keep_s[tt]) {
      float4* dst = (float4*)(buf + (((size_t)(l * 4 + e_s[tt])) * CAPE + pos_s[tt]) * 512);
      dst[idx] = ((const float4*)(QF + ((size_t)l * TTOK + tt) * 512))[idx];
    }
  }
}

// ---------------- expert up-proj + exact gelu (acts via uniform s_loads) ----------------
__global__ __launch_bounds__(256) void k_moe_h(const float* __restrict__ buf, const float* __restrict__ W1,
      const float* __restrict__ B1, float* __restrict__ H) {
  int le = blockIdx.y;             // l*4 + e
  int e = le & 3;
  int col = blockIdx.x * 256 + threadIdx.x;
  const float* act = buf + (size_t)le * 16 * 512;          // wave-uniform
  const float* wp = W1 + (size_t)e * 512 * HIDE + col;
  float acc[16];
#pragma unroll
  for (int c = 0; c < 16; c++) acc[c] = 0.f;
  for (int k0 = 0; k0 < 512; k0 += 4) {
    float4 a[16];
#pragma unroll
    for (int c = 0; c < 16; c++) a[c] = *(const float4*)(act + c * 512 + k0);
#pragma unroll
    for (int j = 0; j < 4; j++) {
      float wv = wp[(size_t)(k0 + j) * HIDE];
#pragma unroll
      for (int c = 0; c < 16; c++) acc[c] = fmaf(((const float*)&a[c])[j], wv, acc[c]);
    }
  }
  float bias = B1[e * HIDE + col];
  float* outp = H + (size_t)le * 16 * HIDE + col;
#pragma unroll
  for (int c = 0; c < 16; c++) {
    float v = acc[c] + bias;
    outp[(size_t)c * HIDE] = 0.5f * v * (1.f + erff(v * 0.70710678118654752f));
  }
}

// ---------------- expert down-proj (k split across 4 waves, LDS reduce) ----------------
__global__ __launch_bounds__(256) void k_moe_y(const float* __restrict__ H, const float* __restrict__ W2,
      const float* __restrict__ B2, float* __restrict__ Y) {
  int le = blockIdx.y;
  int e = le & 3;
  int cl = threadIdx.x & 63, kq = threadIdx.x >> 6;
  int col = blockIdx.x * 64 + cl;
  const float* act = H + (size_t)le * 16 * HIDE + kq * 512;   // wave-uniform
  const float* wp = W2 + (size_t)e * HIDE * 512 + (size_t)(kq * 512) * 512 + col;
  float acc[16];
#pragma unroll
  for (int c = 0; c < 16; c++) acc[c] = 0.f;
  for (int k0 = 0; k0 < 512; k0 += 4) {
    float4 a[16];
#pragma unroll
    for (int c = 0; c < 16; c++) a[c] = *(const float4*)(act + c * HIDE + k0);
#pragma unroll
    for (int j = 0; j < 4; j++) {
      float wv = wp[(size_t)(k0 + j) * 512];
#pragma unroll
      for (int c = 0; c < 16; c++) acc[c] = fmaf(((const float*)&a[c])[j], wv, acc[c]);
    }
  }
  __shared__ float sacc[4][16][64];
#pragma unroll
  for (int c = 0; c < 16; c++) sacc[kq][c][cl] = acc[c];
  __syncthreads();
  if (kq == 0) {
    float bias = B2[e * 512 + col];
#pragma unroll
    for (int c = 0; c < 16; c++) {
      float tot = sacc[0][c][cl] + sacc[1][c][cl] + sacc[2][c][cl] + sacc[3][c][cl] + bias;
      Y[(size_t)le * 16 * 512 + (size_t)c * 512 + col] = tot;
    }
  }
}

// ---------------- gather expert outputs, prefix over layers ----------------
__global__ __launch_bounds__(512) void k_combine(const float* __restrict__ Y, const int* __restrict__ expert,
      const int* __restrict__ pos, const int* __restrict__ keep, const float* __restrict__ gate,
      float* __restrict__ f1, float* __restrict__ f2, float* __restrict__ cur) {
  int t = blockIdx.x;
  int d = threadIdx.x;
  float acc = 0.f;
#pragma unroll
  for (int l = 0; l < LNUM; l++) {
    int idx = l * TTOK + t;
    float v = 0.f;
    if (keep[idx]) {
      int e = expert[idx], p = pos[idx];
      v = Y[(((size_t)(l * 4 + e)) * CAPE + p) * 512 + d] * gate[idx];
    }
    acc += v;
    f1[((size_t)l * TTOK + t) * 512 + d] = acc;
    f2[((size_t)l * TTOK + t) * 512 + d] = 0.f;
  }
  cur[(size_t)t * 512 + d] = acc * 0.25f;
}

// ---------------- GSA attention (8 heads, hd=64), reads fused QKV3 [64][1536] ----------------
__global__ __launch_bounds__(256) void k_gsa_attn(const float* __restrict__ QKV3, float* __restrict__ AO2) {
  int h = blockIdx.x;
  __shared__ float qh[64][65], kh[64][65], vh[64][65];
  __shared__ float ps[4][64];
  for (int i = threadIdx.x; i < 4096; i += 256) {
    int t = i >> 6, d = i & 63;
    qh[t][d] = QKV3[(size_t)t * 1536 + h * 64 + d];
    kh[t][d] = QKV3[(size_t)t * 1536 + 512 + h * 64 + d];
    vh[t][d] = QKV3[(size_t)t * 1536 + 1024 + h * 64 + d];
  }
  __syncthreads();
  int w = threadIdx.x >> 6, lane = threadIdx.x & 63;
  for (int tt = 0; tt < 16; tt++) {
    int t = w * 16 + tt;
    float acc = 0.f;
#pragma unroll 8
    for (int d = 0; d < 64; d++) acc = fmaf(qh[t][d], kh[lane][d], acc);
    acc *= 0.125f;
    float m = acc;
#pragma unroll
    for (int o = 32; o > 0; o >>= 1) m = fmaxf(m, __shfl_xor(m, o, 64));
    float e = __expf(acc - m);
    float den = e;
#pragma unroll
    for (int o = 32; o > 0; o >>= 1) den += __shfl_xor(den, o, 64);
    ps[w][lane] = e / den;
    __syncthreads();
    float o2 = 0.f;
#pragma unroll 8
    for (int s = 0; s < 64; s++) o2 = fmaf(ps[w][s], vh[s][lane], o2);
    AO2[(size_t)t * 512 + h * 64 + lane] = o2;
    __syncthreads();
  }
}

// ---------------- classifier head + hazards + Y_hat + aux + feature2_pre ----------------
__global__ __launch_bounds__(256) void k_final(const float* __restrict__ HB,
      const float* __restrict__ CW, const float* __restrict__ CB,
      const float* __restrict__ ssum, const int* __restrict__ cnt,
      float* __restrict__ out) {
  int tid = threadIdx.x;
  float p0 = 0.f, p1 = 0.f;
  for (int i = tid; i < 16384; i += 256) {
    float h = HB[i];
    p0 = fmaf(h, CW[i], p0);
    p1 = fmaf(h, CW[16384 + i], p1);
  }
  p0 = block_sum256(p0);
  p1 = block_sum256(p1);
  if (tid == 0) {
    float l0 = p0 + CB[0], l1 = p1 + CB[1];
    out[0] = l0; out[1] = l1;
    out[2] = 1.f / (1.f + __expf(-l0));
    out[3] = 1.f / (1.f + __expf(-l1));
    out[4] = (l1 > l0) ? 1.f : 0.f;
    float aux = 0.f;
    for (int i = 0; i < 16; i++) aux += (ssum[i] * (1.f / 64.f)) * ((float)cnt[i] * (1.f / 64.f));
    out[5] = aux * 4.f * 0.01f;
  }
  if (tid < 8) out[O_F2P + tid] = 0.f;
}

extern "C" void kernel_launch(void* const* d_in, const int* in_sizes, int n_in,
                              void* d_out, int out_size, void* d_ws, size_t ws_size,
                              hipStream_t stream) {
  const float* SF    = (const float*)d_in[0];
  const float* TOK   = (const float*)d_in[1];
  const float* LN1G  = (const float*)d_in[2];
  const float* LN1B  = (const float*)d_in[3];
  const float* LN2G  = (const float*)d_in[4];
  const float* LN2B  = (const float*)d_in[5];
  const float* QKVW  = (const float*)d_in[6];
  const float* QKVB  = (const float*)d_in[7];
  const float* OUTW  = (const float*)d_in[8];
  const float* OUTB  = (const float*)d_in[9];
  const float* MLPW  = (const float*)d_in[10];
  const float* MLPB  = (const float*)d_in[11];
  const float* GPW   = (const float*)d_in[12];
  const float* GSIM  = (const float*)d_in[13];
  const float* GTMP  = (const float*)d_in[14];
  const float* EW1   = (const float*)d_in[15];
  const float* EB1   = (const float*)d_in[16];
  const float* EW2   = (const float*)d_in[17];
  const float* EB2   = (const float*)d_in[18];
  const float* GL1G  = (const float*)d_in[19];
  const float* GL1B  = (const float*)d_in[20];
  const float* GQKVW = (const float*)d_in[21];
  const float* GQKVB = (const float*)d_in[22];
  const float* GOUTW = (const float*)d_in[23];
  const float* GOUTB = (const float*)d_in[24];
  const float* GL2G  = (const float*)d_in[25];
  const float* GL2B  = (const float*)d_in[26];
  const float* GFCW  = (const float*)d_in[27];
  const float* GFCB  = (const float*)d_in[28];
  const float* GPJW  = (const float*)d_in[29];
  const float* GPJB  = (const float*)d_in[30];
  const float* BTW   = (const float*)d_in[31];
  const float* BTB   = (const float*)d_in[32];
  const float* CLW   = (const float*)d_in[33];
  const float* CLB   = (const float*)d_in[34];

  float* ws  = (float*)d_ws;
  float* out = (float*)d_out;

  float* BUF  = ws + OFF_BUF;
  float* SSUM = ws + OFF_SSUM;
  int*   CNT  = (int*)(ws + OFF_CNT);
  float* Q    = ws + OFF_Q;
  float* AP   = ws + OFF_AP;
  float* QF   = ws + OFF_QF;
  float* P    = ws + OFF_P;
  float* QKV3 = ws + OFF_QKV3;
  float* XB   = ws + OFF_XB;
  float* HROW = ws + OFF_HROW;
  float* GTD  = ws + OFF_GTD;
  float* HBB  = ws + OFF_HB;
  float* KT   = ws + OFF_KT;
  float* VT   = ws + OFF_VT;
  float* AOSH = ws + OFF_AO;      // shared TN / AO / XN2 / XN3 (sequential lifetimes)
  float* GATE = ws + OFF_GATE;
  int*   EXPI = (int*)(ws + OFF_EXP);
  int*   POSI = (int*)(ws + OFF_POS);
  int*   KEEPI= (int*)(ws + OFF_KEEP);
  float* HEXP = ws + OFF_HEXP;
  float* CUR  = ws + OFF_CUR;
  float* AO2  = ws + OFF_AO2;
  bf16*  AH   = (bf16*)(ws + OFF_AH);
  bf16*  AL   = (bf16*)(ws + OFF_AL);
  bf16*  WH   = (bf16*)(ws + OFF_WH);
  bf16*  WL   = (bf16*)(ws + OFF_WL);
  float* YEXP = ws + OFF_YEXP;    // aliases AH (dead after k_mfma_kv)

  // zero all atomic-GEMM outputs + MoE scratch
  k_zero<<<(ZERO_N + 255) / 256, 256, 0, stream>>>(ws, ZERO_N);
  // K/V projection via split-bf16 MFMA
  k_cvt_a<<<LNUM * NSEQ, 64, 0, stream>>>(SF, LN1G, LN1B, AH, AL);
  k_cvt_w<<<LNUM * 1024, 64, 0, stream>>>(QKVW, WH, WL);
  k_mfma_kv<<<dim3(32, 8, LNUM), 256, 0, stream>>>(AH, AL, WH, WL, QKVB, KT, VT);
  // Q projection: LN(tok) -> TN(=AOSH), then GEMM
  k_ln<<<dim3(TTOK, LNUM), 64, 0, stream>>>(TOK, LN2G, LN2B, AOSH, 512);
  k_gemm64<<<dim3(8, 4, LNUM), 256, 0, stream>>>(AOSH, QKVW, QKVB, nullptr, Q, 512, 512, 1536L*512, 1536, 0);
  // hd=1 attention (fused per-head min/max; overwrites AOSH with AO)
  k_attn<<<dim3(512, LNUM), 256, 0, stream>>>(KT, VT, Q, AOSH);
  // out-proj and mlp
  k_gemm64<<<dim3(8, 4, LNUM), 256, 0, stream>>>(AOSH, OUTW, OUTB, nullptr, AP, 512, 512, 512L*512, 512, 0);
  k_gemm64<<<dim3(8, 4, LNUM), 256, 0, stream>>>(AP, MLPW, MLPB, nullptr, QF, 512, 512, 512L*512, 512, 0);
  // MoE gating + routing + scatter (fused)
  k_gemm64t<<<dim3(4, 4, LNUM), 256, 0, stream>>>(QF, GPW, P, 512, 256);
  k_moe_gate<<<LNUM, 256, 0, stream>>>(P, GSIM, GTMP, QF, GATE, EXPI, POSI, KEEPI, SSUM, CNT, BUF);
  k_moe_h<<<dim3(8, 16), 256, 0, stream>>>(BUF, EW1, EB1, HEXP);
  k_moe_y<<<dim3(8, 16), 256, 0, stream>>>(HEXP, EW2, EB2, YEXP);
  k_combine<<<TTOK, 512, 0, stream>>>(YEXP, EXPI, POSI, KEEPI, GATE, out + O_F1, out + O_F2, CUR);
  // GSA block
  k_ln<<<dim3(TTOK, 1), 64, 0, stream>>>(CUR, GL1G, GL1B, AOSH, 0);             // XN2 in AOSH
  k_gemm64<<<dim3(24, 4, 1), 256, 0, stream>>>(AOSH, GQKVW, GQKVB, nullptr, QKV3, 512, 1536, 0, 0, 0);
  k_gsa_attn<<<8, 256, 0, stream>>>(QKV3, AO2);
  k_gemm64<<<dim3(8, 4, 1), 256, 0, stream>>>(AO2, GOUTW, GOUTB, CUR, XB, 512, 512, 0, 0, 0);
  k_ln<<<dim3(TTOK, 1), 64, 0, stream>>>(XB, GL2G, GL2B, AOSH, 0);              // XN3 in AOSH
  k_gemm64<<<dim3(32, 1, 1), 256, 0, stream>>>(AOSH, GFCW, GFCB, nullptr, HROW, 512, 2048, 0, 0, 1); // +swish
  k_gemm64<<<dim3(8, 16, 1), 256, 0, stream>>>(HROW, GPJW, GPJB, XB, GTD, 2048, 512, 0, 0, 0);
  k_gemm64<<<dim3(4, 4, 1), 256, 0, stream>>>(GTD, BTW, BTB, nullptr, HBB, 512, 256, 0, 0, 0);
  k_final<<<1, 256, 0, stream>>>(HBB, CLW, CLB, SSUM, CNT, out);
}

// Round 6
// 792.799 us; speedup vs baseline: 1.0571x; 1.0571x over previous
//
#include <hip/hip_runtime.h>
#include <math.h>

// LRENet_2: L=4, AD=D=512, T=64, N=4096, NC=2, PROJ=256, HID=2048, CAP=16
#define LNUM 4
#define ADIM 512
#define TTOK 64
#define NSEQ 4096
#define HIDE 2048
#define CAPE 16
#define EPSV 1e-5f

typedef __bf16 bf16;
typedef bf16 bf16x8 __attribute__((ext_vector_type(8)));
typedef float f32x4 __attribute__((ext_vector_type(4)));

// ---------------- workspace layout (float offsets) ----------------
// zero region (atomic-GEMM outputs + MoE buf) first, zeroed every launch
#define OFF_BUF   0
#define OFF_SSUM  (OFF_BUF  + 131072)
#define OFF_CNT   (OFF_SSUM + 16)
#define OFF_Q     (OFF_CNT  + 16)
#define OFF_AP    (OFF_Q    + 131072)
#define OFF_QF    (OFF_AP   + 131072)
#define OFF_P     (OFF_QF   + 131072)
#define OFF_QKV3  (OFF_P    + 65536)
#define OFF_XB    (OFF_QKV3 + 98304)
#define OFF_HROW  (OFF_XB   + 32768)
#define OFF_GTD   (OFF_HROW + 131072)
#define OFF_HB    (OFF_GTD  + 32768)
#define ZERO_N    (OFF_HB   + 16384)
// non-zeroed
#define OFF_KT    ZERO_N
#define OFF_VT    (OFF_KT   + LNUM*512*NSEQ)
#define OFF_AO    (OFF_VT   + LNUM*512*NSEQ)  // shared: TN -> AO -> XN2 -> XN3 (sequential lifetimes)
#define OFF_GATE  (OFF_AO   + 131072)
#define OFF_EXP   (OFF_GATE + 256)
#define OFF_POS   (OFF_EXP  + 256)
#define OFF_KEEP  (OFF_POS  + 256)
#define OFF_HEXP  (OFF_KEEP + 256)
#define OFF_CUR   (OFF_HEXP + LNUM*4*CAPE*HIDE)
#define OFF_AO2   (OFF_CUR  + TTOK*512)
#define OFF_AH    (OFF_AO2  + TTOK*512)   // bf16 (float slots = half count); YEXP aliases (AH dead post-mfma)
#define OFF_AL    (OFF_AH + LNUM*NSEQ*256)
#define OFF_WH    (OFF_AL + LNUM*NSEQ*256)
#define OFF_WL    (OFF_WH + LNUM*1024*256)
#define OFF_YEXP  OFF_AH

// ---------------- output layout (floats) ----------------
#define O_F1   6
#define O_F2   (6 + LNUM*TTOK*512)
#define O_F2P  (O_F2 + LNUM*TTOK*512)

__device__ __forceinline__ float wave_sum(float v) {
#pragma unroll
  for (int o = 32; o > 0; o >>= 1) v += __shfl_down(v, o, 64);
  return v;
}
__device__ __forceinline__ float wave_sum_all(float v) {
#pragma unroll
  for (int o = 32; o > 0; o >>= 1) v += __shfl_xor(v, o, 64);
  return v;
}
__device__ __forceinline__ float block_sum256(float v) {
  __shared__ float r[4];
  v = wave_sum(v);
  int wid = threadIdx.x >> 6, lane = threadIdx.x & 63;
  if (lane == 0) r[wid] = v;
  __syncthreads();
  float s = r[0] + r[1] + r[2] + r[3];
  __syncthreads();
  return s;
}

// ---------------- zero scratch ----------------
__global__ void k_zero(float* __restrict__ p, int n) {
  int i = blockIdx.x * 256 + threadIdx.x;
  if (i < n) p[i] = 0.f;
}

// ---------------- LN + split-bf16 convert of A panel ----------------
__global__ __launch_bounds__(64) void k_cvt_a(const float* __restrict__ SF,
      const float* __restrict__ G, const float* __restrict__ Bta,
      bf16* __restrict__ AH, bf16* __restrict__ AL) {
  int row = blockIdx.x;            // l*4096 + m
  int l = row >> 12, m = row & 4095;
  int lane = threadIdx.x;
  const float* src = SF + (size_t)m * (LNUM * ADIM) + l * ADIM;
  float4 a = *(const float4*)(src + lane * 8);
  float4 b = *(const float4*)(src + lane * 8 + 4);
  float sum = (a.x + a.y) + (a.z + a.w) + (b.x + b.y) + (b.z + b.w);
  float sq = a.x*a.x + a.y*a.y + a.z*a.z + a.w*a.w + b.x*b.x + b.y*b.y + b.z*b.z + b.w*b.w;
  sum = wave_sum_all(sum); sq = wave_sum_all(sq);
  float mu = sum * (1.f / 512.f);
  float rs = rsqrtf(sq * (1.f / 512.f) - mu * mu + EPSV);
  float4 g0 = *(const float4*)(G + l * 512 + lane * 8);
  float4 g1 = *(const float4*)(G + l * 512 + lane * 8 + 4);
  float4 c0 = *(const float4*)(Bta + l * 512 + lane * 8);
  float4 c1 = *(const float4*)(Bta + l * 512 + lane * 8 + 4);
  float x[8];
  x[0] = (a.x - mu) * rs * g0.x + c0.x;  x[1] = (a.y - mu) * rs * g0.y + c0.y;
  x[2] = (a.z - mu) * rs * g0.z + c0.z;  x[3] = (a.w - mu) * rs * g0.w + c0.w;
  x[4] = (b.x - mu) * rs * g1.x + c1.x;  x[5] = (b.y - mu) * rs * g1.y + c1.y;
  x[6] = (b.z - mu) * rs * g1.z + c1.z;  x[7] = (b.w - mu) * rs * g1.w + c1.w;
  bf16x8 vh, vl;
#pragma unroll
  for (int j = 0; j < 8; j++) {
    bf16 h = (bf16)x[j];
    vh[j] = h;
    vl[j] = (bf16)(x[j] - (float)h);
  }
  *(bf16x8*)(AH + (size_t)row * 512 + lane * 8) = vh;
  *(bf16x8*)(AL + (size_t)row * 512 + lane * 8) = vl;
}

// ---------------- split-bf16 convert of W K/V rows ----------------
__global__ __launch_bounds__(64) void k_cvt_w(const float* __restrict__ Wqkv,
      bf16* __restrict__ WH, bf16* __restrict__ WL) {
  int row = blockIdx.x;            // l*1024 + r
  int l = row >> 10, r = row & 1023;
  int lane = threadIdx.x;
  const float* src = Wqkv + (size_t)l * 1536 * 512 + (size_t)(512 + r) * 512 + lane * 8;
  float4 a = *(const float4*)(src);
  float4 b = *(const float4*)(src + 4);
  float x[8] = {a.x, a.y, a.z, a.w, b.x, b.y, b.z, b.w};
  bf16x8 vh, vl;
#pragma unroll
  for (int j = 0; j < 8; j++) {
    bf16 h = (bf16)x[j];
    vh[j] = h;
    vl[j] = (bf16)(x[j] - (float)h);
  }
  *(bf16x8*)(WH + (size_t)row * 512 + lane * 8) = vh;
  *(bf16x8*)(WL + (size_t)row * 512 + lane * 8) = vl;
}

// ---------------- split-bf16 MFMA GEMM -> K^T, V^T ----------------
// LDS row pitch 40 bf16 (80 B): frag ds_read_b128 covers all 32 banks over
// fr=0..7 (2-way over 16 lanes = free) vs 8-way conflict at pitch 32.
#define KVP 40
__global__ __launch_bounds__(256) void k_mfma_kv(
      const bf16* __restrict__ AH, const bf16* __restrict__ AL,
      const bf16* __restrict__ WH, const bf16* __restrict__ WL,
      const float* __restrict__ Bqkv,
      float* __restrict__ KT, float* __restrict__ VT) {
  __shared__ bf16 sAh[128*KVP], sAl[128*KVP], sWh[128*KVP], sWl[128*KVP];
  int l = blockIdx.z;
  int m0 = blockIdx.x * 128, n0 = blockIdx.y * 128;
  int tid = threadIdx.x;
  int lane = tid & 63;
  int w = tid >> 6;
  int wm = w >> 1, wn = w & 1;
  const bf16* gAh = AH + ((size_t)l * 4096 + m0) * 512;
  const bf16* gAl = AL + ((size_t)l * 4096 + m0) * 512;
  const bf16* gWh = WH + ((size_t)l * 1024 + n0) * 512;
  const bf16* gWl = WL + ((size_t)l * 1024 + n0) * 512;
  int ch0 = tid * 2, ch1 = tid * 2 + 1;
  int r0 = ch0 >> 2, q0 = (ch0 & 3) * 8;
  int r1 = ch1 >> 2, q1 = (ch1 & 3) * 8;
  int fr = lane & 15, fq = (lane >> 4) * 8;
  f32x4 acc[4][4] = {};
  for (int k0 = 0; k0 < 512; k0 += 32) {
    *(bf16x8*)&sAh[r0*KVP + q0] = *(const bf16x8*)&gAh[(size_t)r0*512 + k0 + q0];
    *(bf16x8*)&sAh[r1*KVP + q1] = *(const bf16x8*)&gAh[(size_t)r1*512 + k0 + q1];
    *(bf16x8*)&sAl[r0*KVP + q0] = *(const bf16x8*)&gAl[(size_t)r0*512 + k0 + q0];
    *(bf16x8*)&sAl[r1*KVP + q1] = *(const bf16x8*)&gAl[(size_t)r1*512 + k0 + q1];
    *(bf16x8*)&sWh[r0*KVP + q0] = *(const bf16x8*)&gWh[(size_t)r0*512 + k0 + q0];
    *(bf16x8*)&sWh[r1*KVP + q1] = *(const bf16x8*)&gWh[(size_t)r1*512 + k0 + q1];
    *(bf16x8*)&sWl[r0*KVP + q0] = *(const bf16x8*)&gWl[(size_t)r0*512 + k0 + q0];
    *(bf16x8*)&sWl[r1*KVP + q1] = *(const bf16x8*)&gWl[(size_t)r1*512 + k0 + q1];
    __syncthreads();
    bf16x8 ah[4], al[4], bh[4], bl[4];
#pragma unroll
    for (int i = 0; i < 4; i++) {
      ah[i] = *(const bf16x8*)&sAh[(wm*64 + i*16 + fr)*KVP + fq];
      al[i] = *(const bf16x8*)&sAl[(wm*64 + i*16 + fr)*KVP + fq];
      bh[i] = *(const bf16x8*)&sWh[(wn*64 + i*16 + fr)*KVP + fq];
      bl[i] = *(const bf16x8*)&sWl[(wn*64 + i*16 + fr)*KVP + fq];
    }
#pragma unroll
    for (int i = 0; i < 4; i++)
#pragma unroll
      for (int j = 0; j < 4; j++) {
        acc[i][j] = __builtin_amdgcn_mfma_f32_16x16x32_bf16(ah[i], bh[j], acc[i][j], 0, 0, 0);
        acc[i][j] = __builtin_amdgcn_mfma_f32_16x16x32_bf16(ah[i], bl[j], acc[i][j], 0, 0, 0);
        acc[i][j] = __builtin_amdgcn_mfma_f32_16x16x32_bf16(al[i], bh[j], acc[i][j], 0, 0, 0);
      }
    __syncthreads();
  }
#pragma unroll
  for (int j = 0; j < 4; j++) {
    int n = n0 + wn*64 + j*16 + fr;
    float bias = Bqkv[l * 1536 + 512 + n];
    float* base = (n < 512) ? (KT + ((size_t)(l*512 + n)) * 4096)
                            : (VT + ((size_t)(l*512 + n - 512)) * 4096);
#pragma unroll
    for (int i = 0; i < 4; i++) {
      int mb = m0 + wm*64 + i*16 + (lane >> 4) * 4;
      float4 o = make_float4(acc[i][j][0] + bias, acc[i][j][1] + bias,
                             acc[i][j][2] + bias, acc[i][j][3] + bias);
      *(float4*)(base + mb) = o;
    }
  }
}

// ---------------- generic row LayerNorm (64 rows per l) ----------------
__global__ __launch_bounds__(64) void k_ln(const float* __restrict__ IN,
      const float* __restrict__ G, const float* __restrict__ B,
      float* __restrict__ OUT, int gstride) {
  int t = blockIdx.x, l = blockIdx.y;
  int row = l * 64 + t;
  int lane = threadIdx.x;
  const float* x = IN + (size_t)row * 512 + lane * 8;
  float4 a = ((const float4*)x)[0], b = ((const float4*)x)[1];
  float sum = (a.x + a.y) + (a.z + a.w) + (b.x + b.y) + (b.z + b.w);
  float sq = a.x*a.x + a.y*a.y + a.z*a.z + a.w*a.w + b.x*b.x + b.y*b.y + b.z*b.z + b.w*b.w;
  sum = wave_sum_all(sum); sq = wave_sum_all(sq);
  float mu = sum * (1.f / 512.f);
  float rs = rsqrtf(sq * (1.f / 512.f) - mu * mu + EPSV);
  const float* gp = G + l * gstride + lane * 8;
  const float* bp = B + l * gstride + lane * 8;
  float4 g0 = ((const float4*)gp)[0], g1 = ((const float4*)gp)[1];
  float4 c0 = ((const float4*)bp)[0], c1 = ((const float4*)bp)[1];
  float4 o0, o1;
  o0.x = (a.x - mu) * rs * g0.x + c0.x;  o0.y = (a.y - mu) * rs * g0.y + c0.y;
  o0.z = (a.z - mu) * rs * g0.z + c0.z;  o0.w = (a.w - mu) * rs * g0.w + c0.w;
  o1.x = (b.x - mu) * rs * g1.x + c1.x;  o1.y = (b.y - mu) * rs * g1.y + c1.y;
  o1.z = (b.z - mu) * rs * g1.z + c1.z;  o1.w = (b.w - mu) * rs * g1.w + c1.w;
  float* op = OUT + (size_t)row * 512 + lane * 8;
  ((float4*)op)[0] = o0; ((float4*)op)[1] = o1;
}

// ---------------- generic split-K GEMM: OUT[64t x N] (+)= IN[64t x K] @ W[N x K]^T ----------------
__global__ __launch_bounds__(256) void k_gemm64(
      const float* __restrict__ IN, const float* __restrict__ W,
      const float* __restrict__ BIAS, const float* __restrict__ RES,
      float* __restrict__ OUT, int K, int N, long wl, int bl, int act) {
  int l = blockIdx.z;
  int n0 = blockIdx.x * 64;
  bool split = (gridDim.y > 1);
  int kcBeg = blockIdx.y * 128;
  int kcEnd = split ? kcBeg + 128 : K;
  const float* INl = IN + (size_t)l * 64 * K;
  const float* Wl  = W + (size_t)l * wl;
  float* OUTl = OUT + (size_t)l * 64 * N;
  __shared__ float sA[64][68], sB[64][68];
  int tid = threadIdx.x;
  int tx = tid & 15, ty = tid >> 4;
  float acc[4][4];
  if (blockIdx.y == 0) {
#pragma unroll
    for (int j = 0; j < 4; j++) {
      float bv = BIAS ? BIAS[bl * l + n0 + tx*4 + j] : 0.f;
#pragma unroll
      for (int i = 0; i < 4; i++)
        acc[i][j] = bv + (RES ? RES[((size_t)l*64 + ty*4 + i) * N + n0 + tx*4 + j] : 0.f);
    }
  } else {
#pragma unroll
    for (int i = 0; i < 4; i++)
#pragma unroll
      for (int j = 0; j < 4; j++) acc[i][j] = 0.f;
  }
  for (int kc = kcBeg; kc < kcEnd; kc += 64) {
    for (int i = tid; i < 1024; i += 256) {
      int r = i >> 4;
      int kq = i & 15;
      float4 av = *(const float4*)(INl + (size_t)r * K + kc + kq*4);
      sA[kq*4+0][r] = av.x; sA[kq*4+1][r] = av.y; sA[kq*4+2][r] = av.z; sA[kq*4+3][r] = av.w;
      float4 bv = *(const float4*)(Wl + (size_t)(n0 + r) * K + kc + kq*4);
      sB[kq*4+0][r] = bv.x; sB[kq*4+1][r] = bv.y; sB[kq*4+2][r] = bv.z; sB[kq*4+3][r] = bv.w;
    }
    __syncthreads();
#pragma unroll 8
    for (int kk = 0; kk < 64; kk++) {
      float4 a4 = *(const float4*)&sA[kk][ty*4];
      float4 b4 = *(const float4*)&sB[kk][tx*4];
      float a[4] = {a4.x,a4.y,a4.z,a4.w}, b[4] = {b4.x,b4.y,b4.z,b4.w};
#pragma unroll
      for (int i = 0; i < 4; i++)
#pragma unroll
        for (int j = 0; j < 4; j++) acc[i][j] = fmaf(a[i], b[j], acc[i][j]);
    }
    __syncthreads();
  }
  if (split) {
#pragma unroll
    for (int i = 0; i < 4; i++)
#pragma unroll
      for (int j = 0; j < 4; j++)
        atomicAdd(&OUTl[(size_t)(ty*4+i) * N + n0 + tx*4 + j], acc[i][j]);
  } else {
#pragma unroll
    for (int i = 0; i < 4; i++)
#pragma unroll
      for (int j = 0; j < 4; j++) {
        float o = acc[i][j];
        if (act == 1) o = o / (1.f + __expf(-1.702f * o));
        OUTl[(size_t)(ty*4+i) * N + n0 + tx*4 + j] = o;
      }
  }
}

// ---------------- transposed-W variant: W stored [K][N] (for gate proj) ----------------
__global__ __launch_bounds__(256) void k_gemm64t(
      const float* __restrict__ IN, const float* __restrict__ W,
      float* __restrict__ OUT, int K, int N) {
  int l = blockIdx.z;
  int n0 = blockIdx.x * 64;
  int kc0 = blockIdx.y * 128;
  const float* INl = IN + (size_t)l * 64 * K;
  float* OUTl = OUT + (size_t)l * 64 * N;
  __shared__ float sA[64][68], sB[64][68];
  int tid = threadIdx.x;
  int tx = tid & 15, ty = tid >> 4;
  float acc[4][4] = {};
  for (int kc = kc0; kc < kc0 + 128; kc += 64) {
    for (int i = tid; i < 1024; i += 256) {
      int r = i >> 4;
      int kq = i & 15;
      float4 av = *(const float4*)(INl + (size_t)r * K + kc + kq*4);
      sA[kq*4+0][r] = av.x; sA[kq*4+1][r] = av.y; sA[kq*4+2][r] = av.z; sA[kq*4+3][r] = av.w;
      float4 bv = *(const float4*)(W + (size_t)(kc + r) * N + n0 + kq*4);
      *(float4*)&sB[r][kq*4] = bv;
    }
    __syncthreads();
#pragma unroll 8
    for (int kk = 0; kk < 64; kk++) {
      float4 a4 = *(const float4*)&sA[kk][ty*4];
      float4 b4 = *(const float4*)&sB[kk][tx*4];
      float a[4] = {a4.x,a4.y,a4.z,a4.w}, b[4] = {b4.x,b4.y,b4.z,b4.w};
#pragma unroll
      for (int i = 0; i < 4; i++)
#pragma unroll
        for (int j = 0; j < 4; j++) acc[i][j] = fmaf(a[i], b[j], acc[i][j]);
    }
    __syncthreads();
  }
#pragma unroll
  for (int i = 0; i < 4; i++)
#pragma unroll
    for (int j = 0; j < 4; j++)
      atomicAdd(&OUTl[(size_t)(ty*4+i) * N + n0 + tx*4 + j], acc[i][j]);
}

// ---------------- hd=1 attention: register K/V, fused min/max, LDS partial reduce ----------------
// __expf (native v_exp, 2 instrs) — NOT exp2f (libm, ~8 instrs: round-5 regression).
// 8-token chunks: LDS 17 KB -> higher occupancy than round-5's 33 KB.
__global__ __launch_bounds__(256) void k_attn(const float* __restrict__ KT, const float* __restrict__ VT,
      const float* __restrict__ Q, float* __restrict__ AO) {
  int h = blockIdx.x, l = blockIdx.y;
  int tid = threadIdx.x;
  int w = tid >> 6, lane = tid & 63;
  __shared__ float2 sacc[4][8][66];
  __shared__ float wmx[4], wmn[4];
  size_t base = ((size_t)(l * 512 + h)) * 4096 + w * 1024;
  float kv[16], vv[16];
#pragma unroll
  for (int c = 0; c < 4; c++) {
    *(float4*)&kv[c*4] = *(const float4*)(KT + base + c * 256 + lane * 4);
    *(float4*)&vv[c*4] = *(const float4*)(VT + base + c * 256 + lane * 4);
  }
  // fused per-head k min/max
  float mx = kv[0], mn = kv[0];
#pragma unroll
  for (int i = 1; i < 16; i++) { mx = fmaxf(mx, kv[i]); mn = fminf(mn, kv[i]); }
#pragma unroll
  for (int o = 32; o > 0; o >>= 1) {
    mx = fmaxf(mx, __shfl_xor(mx, o, 64));
    mn = fminf(mn, __shfl_xor(mn, o, 64));
  }
  if (lane == 0) { wmx[w] = mx; wmn[w] = mn; }
  __syncthreads();
  float km = fmaxf(fmaxf(wmx[0], wmx[1]), fmaxf(wmx[2], wmx[3]));
  float kn = fminf(fminf(wmn[0], wmn[1]), fminf(wmn[2], wmn[3]));
  float q_own = Q[((size_t)l * TTOK + lane) * 512 + h];
  float m_own = (q_own >= 0.f) ? q_own * km : q_own * kn;   // exact softmax max (hd=1)
  int rt = tid >> 5, rj = tid & 31;
  for (int cc = 0; cc < 8; cc++) {
    for (int tt = 0; tt < 8; tt++) {
      int t = cc * 8 + tt;
      float qt = __shfl(q_own, t, 64);
      float mt = __shfl(m_own, t, 64);
      float den = 0.f, num = 0.f;
#pragma unroll
      for (int i = 0; i < 16; i++) {
        float e = __expf(fmaf(qt, kv[i], -mt));
        den += e;
        num = fmaf(e, vv[i], num);
      }
      sacc[w][tt][lane] = make_float2(den, num);
    }
    __syncthreads();
    // reduce 256 partials per t: 32 threads per t, 8 reads each, then shfl width-32
    float2 a = make_float2(0.f, 0.f);
#pragma unroll
    for (int g = 0; g < 4; g++)
#pragma unroll
      for (int s2 = 0; s2 < 2; s2++) {
        float2 v = sacc[g][rt][rj + 32 * s2];
        a.x += v.x; a.y += v.y;
      }
#pragma unroll
    for (int o = 16; o > 0; o >>= 1) {
      a.x += __shfl_down(a.x, o, 32);
      a.y += __shfl_down(a.y, o, 32);
    }
    if (rj == 0) {
      int t = cc * 8 + rt;
      AO[((size_t)l * TTOK + t) * 512 + h] = a.y / a.x;
    }
    __syncthreads();
  }
}

// ---------------- fused MoE gate + route + scatter (one block per layer) ----------------
__global__ __launch_bounds__(256) void k_moe_gate(const float* __restrict__ P,
      const float* __restrict__ SIM, const float* __restrict__ TEMP,
      const float* __restrict__ QF,
      float* __restrict__ gate, int* __restrict__ expert,
      int* __restrict__ pos, int* __restrict__ keep,
      float* __restrict__ ssum, int* __restrict__ cnt, float* __restrict__ buf) {
  int l = blockIdx.x;
  int tid = threadIdx.x;
  int t = tid >> 2, q = tid & 3;     // 4 threads per token, 64 proj dims each
  __shared__ float score_s[4][64];
  __shared__ float g_s[64];
  __shared__ int e_s[64], keep_s[64], pos_s[64];
  const float* prow = P + ((size_t)(l * 64 + t)) * 256 + q * 64;
  float ss = 0.f, le[4] = {}, ne[4] = {};
  for (int j = 0; j < 64; j++) {
    float pv = prow[j];
    ss = fmaf(pv, pv, ss);
    float4 s4 = *(const float4*)(SIM + (size_t)(q * 64 + j) * 4);
    le[0] = fmaf(pv, s4.x, le[0]); le[1] = fmaf(pv, s4.y, le[1]);
    le[2] = fmaf(pv, s4.z, le[2]); le[3] = fmaf(pv, s4.w, le[3]);
    ne[0] = fmaf(s4.x, s4.x, ne[0]); ne[1] = fmaf(s4.y, s4.y, ne[1]);
    ne[2] = fmaf(s4.z, s4.z, ne[2]); ne[3] = fmaf(s4.w, s4.w, ne[3]);
  }
#pragma unroll
  for (int o = 2; o > 0; o >>= 1) {
    ss += __shfl_xor(ss, o, 4);
#pragma unroll
    for (int e = 0; e < 4; e++) { le[e] += __shfl_xor(le[e], o, 4); ne[e] += __shfl_xor(ne[e], o, 4); }
  }
  if (q == 0) {
    float invp = 1.f / (sqrtf(ss) + 1e-8f);
    float scale = __expf(fminf(TEMP[0], 4.6051701859880914f));  // min(temp, log 100)
    float lg[4];
#pragma unroll
    for (int e = 0; e < 4; e++) lg[e] = le[e] * invp / (sqrtf(ne[e]) + 1e-8f) * scale;
    int best = 0; float bv = lg[0];
    if (lg[1] > bv) { best = 1; bv = lg[1]; }
    if (lg[2] > bv) { best = 2; bv = lg[2]; }
    if (lg[3] > bv) { best = 3; bv = lg[3]; }
    float mx = fmaxf(fmaxf(lg[0], lg[1]), fmaxf(lg[2], lg[3]));
    float e0 = __expf(lg[0]-mx), e1 = __expf(lg[1]-mx), e2 = __expf(lg[2]-mx), e3 = __expf(lg[3]-mx);
    float inv = 1.f / (e0 + e1 + e2 + e3);
    score_s[0][t] = e0*inv; score_s[1][t] = e1*inv; score_s[2][t] = e2*inv; score_s[3][t] = e3*inv;
    float sb = score_s[best][t];
    g_s[t] = sb; e_s[t] = best;
    gate[l * TTOK + t] = sb;
    expert[l * TTOK + t] = best;
  }
  __syncthreads();
  if (tid < 64) {
    float gt = g_s[tid]; int et = e_s[tid];
    int p = 0;
    for (int u = 0; u < 64; u++)
      if (e_s[u] == et && (g_s[u] > gt || (g_s[u] == gt && u < tid))) p++;
    pos_s[tid] = p; keep_s[tid] = (p < CAPE) ? 1 : 0;
    pos[l * TTOK + tid] = p;
    keep[l * TTOK + tid] = (p < CAPE) ? 1 : 0;
  } else if (tid < 68) {
    int e = tid - 64;
    float s = 0.f; int c = 0;
    for (int u = 0; u < 64; u++) { s += score_s[e][u]; c += (e_s[u] == e); }
    ssum[l * 4 + e] = s;
    cnt[l * 4 + e] = c;
  }
  __syncthreads();
  int which = tid >> 7, idx = tid & 127;   // 2 tokens per iteration, 128 float4 each
  for (int tb = 0; tb < 64; tb += 2) {
    int tt = tb + which;
    if (keep_s[tt]) {
      float4* dst = (float4*)(buf + (((size_t)(l * 4 + e_s[tt])) * CAPE + pos_s[tt]) * 512);
      dst[idx] = ((const float4*)(QF + ((size_t)l * TTOK + tt) * 512))[idx];
    }
  }
}

// ---------------- expert up-proj + exact gelu (acts via uniform s_loads) ----------------
__global__ __launch_bounds__(256) void k_moe_h(const float* __restrict__ buf, const float* __restrict__ W1,
      const float* __restrict__ B1, float* __restrict__ H) {
  int le = blockIdx.y;             // l*4 + e
  int e = le & 3;
  int col = blockIdx.x * 256 + threadIdx.x;
  const float* act = buf + (size_t)le * 16 * 512;          // wave-uniform
  const float* wp = W1 + (size_t)e * 512 * HIDE + col;
  float acc[16];
#pragma unroll
  for (int c = 0; c < 16; c++) acc[c] = 0.f;
  for (int k0 = 0; k0 < 512; k0 += 4) {
    float4 a[16];
#pragma unroll
    for (int c = 0; c < 16; c++) a[c] = *(const float4*)(act + c * 512 + k0);
#pragma unroll
    for (int j = 0; j < 4; j++) {
      float wv = wp[(size_t)(k0 + j) * HIDE];
#pragma unroll
      for (int c = 0; c < 16; c++) acc[c] = fmaf(((const float*)&a[c])[j], wv, acc[c]);
    }
  }
  float bias = B1[e * HIDE + col];
  float* outp = H + (size_t)le * 16 * HIDE + col;
#pragma unroll
  for (int c = 0; c < 16; c++) {
    float v = acc[c] + bias;
    outp[(size_t)c * HIDE] = 0.5f * v * (1.f + erff(v * 0.70710678118654752f));
  }
}

// ---------------- expert down-proj (k split across 4 waves, LDS reduce) ----------------
__global__ __launch_bounds__(256) void k_moe_y(const float* __restrict__ H, const float* __restrict__ W2,
      const float* __restrict__ B2, float* __restrict__ Y) {
  int le = blockIdx.y;
  int e = le & 3;
  int cl = threadIdx.x & 63, kq = threadIdx.x >> 6;
  int col = blockIdx.x * 64 + cl;
  const float* act = H + (size_t)le * 16 * HIDE + kq * 512;   // wave-uniform
  const float* wp = W2 + (size_t)e * HIDE * 512 + (size_t)(kq * 512) * 512 + col;
  float acc[16];
#pragma unroll
  for (int c = 0; c < 16; c++) acc[c] = 0.f;
  for (int k0 = 0; k0 < 512; k0 += 4) {
    float4 a[16];
#pragma unroll
    for (int c = 0; c < 16; c++) a[c] = *(const float4*)(act + c * HIDE + k0);
#pragma unroll
    for (int j = 0; j < 4; j++) {
      float wv = wp[(size_t)(k0 + j) * 512];
#pragma unroll
      for (int c = 0; c < 16; c++) acc[c] = fmaf(((const float*)&a[c])[j], wv, acc[c]);
    }
  }
  __shared__ float sacc[4][16][64];
#pragma unroll
  for (int c = 0; c < 16; c++) sacc[kq][c][cl] = acc[c];
  __syncthreads();
  if (kq == 0) {
    float bias = B2[e * 512 + col];
#pragma unroll
    for (int c = 0; c < 16; c++) {
      float tot = sacc[0][c][cl] + sacc[1][c][cl] + sacc[2][c][cl] + sacc[3][c][cl] + bias;
      Y[(size_t)le * 16 * 512 + (size_t)c * 512 + col] = tot;
    }
  }
}

// ---------------- gather expert outputs, prefix over layers ----------------
__global__ __launch_bounds__(512) void k_combine(const float* __restrict__ Y, const int* __restrict__ expert,
      const int* __restrict__ pos, const int* __restrict__ keep, const float* __restrict__ gate,
      float* __restrict__ f1, float* __restrict__ f2, float* __restrict__ cur) {
  int t = blockIdx.x;
  int d = threadIdx.x;
  float acc = 0.f;
#pragma unroll
  for (int l = 0; l < LNUM; l++) {
    int idx = l * TTOK + t;
    float v = 0.f;
    if (keep[idx]) {
      int e = expert[idx], p = pos[idx];
      v = Y[(((size_t)(l * 4 + e)) * CAPE + p) * 512 + d] * gate[idx];
    }
    acc += v;
    f1[((size_t)l * TTOK + t) * 512 + d] = acc;
    f2[((size_t)l * TTOK + t) * 512 + d] = 0.f;
  }
  cur[(size_t)t * 512 + d] = acc * 0.25f;
}

// ---------------- GSA attention (8 heads, hd=64), reads fused QKV3 [64][1536] ----------------
__global__ __launch_bounds__(256) void k_gsa_attn(const float* __restrict__ QKV3, float* __restrict__ AO2) {
  int h = blockIdx.x;
  __shared__ float qh[64][65], kh[64][65], vh[64][65];
  __shared__ float ps[4][64];
  for (int i = threadIdx.x; i < 4096; i += 256) {
    int t = i >> 6, d = i & 63;
    qh[t][d] = QKV3[(size_t)t * 1536 + h * 64 + d];
    kh[t][d] = QKV3[(size_t)t * 1536 + 512 + h * 64 + d];
    vh[t][d] = QKV3[(size_t)t * 1536 + 1024 + h * 64 + d];
  }
  __syncthreads();
  int w = threadIdx.x >> 6, lane = threadIdx.x & 63;
  for (int tt = 0; tt < 16; tt++) {
    int t = w * 16 + tt;
    float acc = 0.f;
#pragma unroll 8
    for (int d = 0; d < 64; d++) acc = fmaf(qh[t][d], kh[lane][d], acc);
    acc *= 0.125f;
    float m = acc;
#pragma unroll
    for (int o = 32; o > 0; o >>= 1) m = fmaxf(m, __shfl_xor(m, o, 64));
    float e = __expf(acc - m);
    float den = e;
#pragma unroll
    for (int o = 32; o > 0; o >>= 1) den += __shfl_xor(den, o, 64);
    ps[w][lane] = e / den;
    __syncthreads();
    float o2 = 0.f;
#pragma unroll 8
    for (int s = 0; s < 64; s++) o2 = fmaf(ps[w][s], vh[s][lane], o2);
    AO2[(size_t)t * 512 + h * 64 + lane] = o2;
    __syncthreads();
  }
}

// ---------------- classifier head + hazards + Y_hat + aux + feature2_pre ----------------
__global__ __launch_bounds__(256) void k_final(const float* __restrict__ HB,
      const float* __restrict__ CW, const float* __restrict__ CB,
      const float* __restrict__ ssum, const int* __restrict__ cnt,
      float* __restrict__ out) {
  int tid = threadIdx.x;
  float p0 = 0.f, p1 = 0.f;
  for (int i = tid; i < 16384; i += 256) {
    float h = HB[i];
    p0 = fmaf(h, CW[i], p0);
    p1 = fmaf(h, CW[16384 + i], p1);
  }
  p0 = block_sum256(p0);
  p1 = block_sum256(p1);
  if (tid == 0) {
    float l0 = p0 + CB[0], l1 = p1 + CB[1];
    out[0] = l0; out[1] = l1;
    out[2] = 1.f / (1.f + __expf(-l0));
    out[3] = 1.f / (1.f + __expf(-l1));
    out[4] = (l1 > l0) ? 1.f : 0.f;
    float aux = 0.f;
    for (int i = 0; i < 16; i++) aux += (ssum[i] * (1.f / 64.f)) * ((float)cnt[i] * (1.f / 64.f));
    out[5] = aux * 4.f * 0.01f;
  }
  if (tid < 8) out[O_F2P + tid] = 0.f;
}

extern "C" void kernel_launch(void* const* d_in, const int* in_sizes, int n_in,
                              void* d_out, int out_size, void* d_ws, size_t ws_size,
                              hipStream_t stream) {
  const float* SF    = (const float*)d_in[0];
  const float* TOK   = (const float*)d_in[1];
  const float* LN1G  = (const float*)d_in[2];
  const float* LN1B  = (const float*)d_in[3];
  const float* LN2G  = (const float*)d_in[4];
  const float* LN2B  = (const float*)d_in[5];
  const float* QKVW  = (const float*)d_in[6];
  const float* QKVB  = (const float*)d_in[7];
  const float* OUTW  = (const float*)d_in[8];
  const float* OUTB  = (const float*)d_in[9];
  const float* MLPW  = (const float*)d_in[10];
  const float* MLPB  = (const float*)d_in[11];
  const float* GPW   = (const float*)d_in[12];
  const float* GSIM  = (const float*)d_in[13];
  const float* GTMP  = (const float*)d_in[14];
  const float* EW1   = (const float*)d_in[15];
  const float* EB1   = (const float*)d_in[16];
  const float* EW2   = (const float*)d_in[17];
  const float* EB2   = (const float*)d_in[18];
  const float* GL1G  = (const float*)d_in[19];
  const float* GL1B  = (const float*)d_in[20];
  const float* GQKVW = (const float*)d_in[21];
  const float* GQKVB = (const float*)d_in[22];
  const float* GOUTW = (const float*)d_in[23];
  const float* GOUTB = (const float*)d_in[24];
  const float* GL2G  = (const float*)d_in[25];
  const float* GL2B  = (const float*)d_in[26];
  const float* GFCW  = (const float*)d_in[27];
  const float* GFCB  = (const float*)d_in[28];
  const float* GPJW  = (const float*)d_in[29];
  const float* GPJB  = (const float*)d_in[30];
  const float* BTW   = (const float*)d_in[31];
  const float* BTB   = (const float*)d_in[32];
  const float* CLW   = (const float*)d_in[33];
  const float* CLB   = (const float*)d_in[34];

  float* ws  = (float*)d_ws;
  float* out = (float*)d_out;

  float* BUF  = ws + OFF_BUF;
  float* SSUM = ws + OFF_SSUM;
  int*   CNT  = (int*)(ws + OFF_CNT);
  float* Q    = ws + OFF_Q;
  float* AP   = ws + OFF_AP;
  float* QF   = ws + OFF_QF;
  float* P    = ws + OFF_P;
  float* QKV3 = ws + OFF_QKV3;
  float* XB   = ws + OFF_XB;
  float* HROW = ws + OFF_HROW;
  float* GTD  = ws + OFF_GTD;
  float* HBB  = ws + OFF_HB;
  float* KT   = ws + OFF_KT;
  float* VT   = ws + OFF_VT;
  float* AOSH = ws + OFF_AO;      // shared TN / AO / XN2 / XN3 (sequential lifetimes)
  float* GATE = ws + OFF_GATE;
  int*   EXPI = (int*)(ws + OFF_EXP);
  int*   POSI = (int*)(ws + OFF_POS);
  int*   KEEPI= (int*)(ws + OFF_KEEP);
  float* HEXP = ws + OFF_HEXP;
  float* CUR  = ws + OFF_CUR;
  float* AO2  = ws + OFF_AO2;
  bf16*  AH   = (bf16*)(ws + OFF_AH);
  bf16*  AL   = (bf16*)(ws + OFF_AL);
  bf16*  WH   = (bf16*)(ws + OFF_WH);
  bf16*  WL   = (bf16*)(ws + OFF_WL);
  float* YEXP = ws + OFF_YEXP;    // aliases AH (dead after k_mfma_kv)

  // zero all atomic-GEMM outputs + MoE scratch
  k_zero<<<(ZERO_N + 255) / 256, 256, 0, stream>>>(ws, ZERO_N);
  // K/V projection via split-bf16 MFMA
  k_cvt_a<<<LNUM * NSEQ, 64, 0, stream>>>(SF, LN1G, LN1B, AH, AL);
  k_cvt_w<<<LNUM * 1024, 64, 0, stream>>>(QKVW, WH, WL);
  k_mfma_kv<<<dim3(32, 8, LNUM), 256, 0, stream>>>(AH, AL, WH, WL, QKVB, KT, VT);
  // Q projection: LN(tok) -> TN(=AOSH), then GEMM
  k_ln<<<dim3(TTOK, LNUM), 64, 0, stream>>>(TOK, LN2G, LN2B, AOSH, 512);
  k_gemm64<<<dim3(8, 4, LNUM), 256, 0, stream>>>(AOSH, QKVW, QKVB, nullptr, Q, 512, 512, 1536L*512, 1536, 0);
  // hd=1 attention (fused per-head min/max; overwrites AOSH with AO)
  k_attn<<<dim3(512, LNUM), 256, 0, stream>>>(KT, VT, Q, AOSH);
  // out-proj and mlp
  k_gemm64<<<dim3(8, 4, LNUM), 256, 0, stream>>>(AOSH, OUTW, OUTB, nullptr, AP, 512, 512, 512L*512, 512, 0);
  k_gemm64<<<dim3(8, 4, LNUM), 256, 0, stream>>>(AP, MLPW, MLPB, nullptr, QF, 512, 512, 512L*512, 512, 0);
  // MoE gating + routing + scatter (fused)
  k_gemm64t<<<dim3(4, 4, LNUM), 256, 0, stream>>>(QF, GPW, P, 512, 256);
  k_moe_gate<<<LNUM, 256, 0, stream>>>(P, GSIM, GTMP, QF, GATE, EXPI, POSI, KEEPI, SSUM, CNT, BUF);
  k_moe_h<<<dim3(8, 16), 256, 0, stream>>>(BUF, EW1, EB1, HEXP);
  k_moe_y<<<dim3(8, 16), 256, 0, stream>>>(HEXP, EW2, EB2, YEXP);
  k_combine<<<TTOK, 512, 0, stream>>>(YEXP, EXPI, POSI, KEEPI, GATE, out + O_F1, out + O_F2, CUR);
  // GSA block
  k_ln<<<dim3(TTOK, 1), 64, 0, stream>>>(CUR, GL1G, GL1B, AOSH, 0);             // XN2 in AOSH
  k_gemm64<<<dim3(24, 4, 1), 256, 0, stream>>>(AOSH, GQKVW, GQKVB, nullptr, QKV3, 512, 1536, 0, 0, 0);
  k_gsa_attn<<<8, 256, 0, stream>>>(QKV3, AO2);
  k_gemm64<<<dim3(8, 4, 1), 256, 0, stream>>>(AO2, GOUTW, GOUTB, CUR, XB, 512, 512, 0, 0, 0);
  k_ln<<<dim3(TTOK, 1), 64, 0, stream>>>(XB, GL2G, GL2B, AOSH, 0);              // XN3 in AOSH
  k_gemm64<<<dim3(32, 1, 1), 256, 0, stream>>>(AOSH, GFCW, GFCB, nullptr, HROW, 512, 2048, 0, 0, 1); // +swish
  k_gemm64<<<dim3(8, 16, 1), 256, 0, stream>>>(HROW, GPJW, GPJB, XB, GTD, 2048, 512, 0, 0, 0);
  k_gemm64<<<dim3(4, 4, 1), 256, 0, stream>>>(GTD, BTW, BTB, nullptr, HBB, 512, 256, 0, 0, 0);
  k_final<<<1, 256, 0, stream>>>(HBB, CLW, CLB, SSUM, CNT, out);
}